// Round 1
// baseline (224.977 us; speedup 1.0000x reference)
//
#include <hip/hip_runtime.h>

// QuantizedLinear(5, 10, bits=2): out[N,10] = x[N,5] @ w_deq.T + bias
// w_deq = fake_quant(w): per-row scale = max(|w_row|)/qmax (qmax=1), clip(round(w/s), -2, 1)*s
// Memory-bound: 80 MB read + 160 MB write.

constexpr int IN_F = 5;
constexpr int OUT_F = 10;
constexpr int BLOCK = 256;
constexpr int TOK_PER_TILE = 1024;   // tokens per block-tile

__global__ __launch_bounds__(BLOCK) void qlinear_kernel(
    const float* __restrict__ x,
    const float* __restrict__ w,
    const float* __restrict__ bias,
    float* __restrict__ out,
    int n_tokens)
{
    __shared__ float wdq[OUT_F * IN_F];
    __shared__ float bsh[OUT_F];
    __shared__ float xs[TOK_PER_TILE * IN_F];    // 5120 floats = 20 KB
    __shared__ float os[TOK_PER_TILE * OUT_F];   // 10240 floats = 40 KB

    const int tid = threadIdx.x;

    // --- dequantize tiny weight into LDS (threads 0..9, one output row each) ---
    if (tid < OUT_F) {
        float row[IN_F];
        float mx = 0.0f;
        #pragma unroll
        for (int j = 0; j < IN_F; ++j) {
            row[j] = w[tid * IN_F + j];
            mx = fmaxf(mx, fabsf(row[j]));
        }
        // bits=2: qmax = 1, qmin = -2; scale = max|w| / qmax
        float scale = fmaxf(mx, 1e-8f);
        #pragma unroll
        for (int j = 0; j < IN_F; ++j) {
            float q = rintf(row[j] / scale);       // round half-to-even, matches jnp.round
            q = fminf(fmaxf(q, -2.0f), 1.0f);
            wdq[tid * IN_F + j] = q * scale;
        }
        bsh[tid] = bias[tid];
    }
    __syncthreads();

    const long tok0 = (long)blockIdx.x * TOK_PER_TILE;
    const bool full = (tok0 + TOK_PER_TILE) <= (long)n_tokens;

    // --- stage x tile into LDS, coalesced ---
    const long xbase = tok0 * IN_F;
    if (full) {
        const float4* __restrict__ xg = (const float4*)(x + xbase);
        float4* xls = (float4*)xs;
        #pragma unroll
        for (int k = 0; k < (TOK_PER_TILE * IN_F / 4) / BLOCK; ++k)   // 5 iters
            xls[tid + k * BLOCK] = xg[tid + k * BLOCK];
    } else {
        const long xtotal = (long)n_tokens * IN_F;
        for (int k = tid; k < TOK_PER_TILE * IN_F; k += BLOCK) {
            long gi = xbase + k;
            xs[k] = (gi < xtotal) ? x[gi] : 0.0f;
        }
    }
    __syncthreads();

    // --- compute: 4 tokens per thread (LDS read stride 5 = odd -> conflict-free) ---
    #pragma unroll
    for (int m = 0; m < TOK_PER_TILE / BLOCK; ++m) {
        const int lt = tid + m * BLOCK;
        float xv[IN_F];
        #pragma unroll
        for (int j = 0; j < IN_F; ++j) xv[j] = xs[lt * IN_F + j];
        #pragma unroll
        for (int o = 0; o < OUT_F; ++o) {
            float acc = bsh[o];
            #pragma unroll
            for (int j = 0; j < IN_F; ++j)
                acc = fmaf(xv[j], wdq[o * IN_F + j], acc);
            os[lt * OUT_F + o] = acc;
        }
    }
    __syncthreads();

    // --- stream out tile to global, coalesced ---
    const long obase = tok0 * OUT_F;
    if (full) {
        const float4* ols = (const float4*)os;
        float4* __restrict__ og = (float4*)(out + obase);
        #pragma unroll
        for (int k = 0; k < (TOK_PER_TILE * OUT_F / 4) / BLOCK; ++k)  // 10 iters
            og[tid + k * BLOCK] = ols[tid + k * BLOCK];
    } else {
        const long ototal = (long)n_tokens * OUT_F;
        for (int k = tid; k < TOK_PER_TILE * OUT_F; k += BLOCK) {
            long gi = obase + k;
            if (gi < ototal) out[gi] = os[k];
        }
    }
}

extern "C" void kernel_launch(void* const* d_in, const int* in_sizes, int n_in,
                              void* d_out, int out_size, void* d_ws, size_t ws_size,
                              hipStream_t stream) {
    const float* x    = (const float*)d_in[0];   // [N, 5]
    const float* wgt  = (const float*)d_in[1];   // [10, 5]
    const float* bias = (const float*)d_in[2];   // [10]
    float* out = (float*)d_out;                  // [N, 10]

    const int n_tokens = in_sizes[0] / IN_F;     // 4,000,000
    const int tiles = (n_tokens + TOK_PER_TILE - 1) / TOK_PER_TILE;  // 3907

    qlinear_kernel<<<tiles, BLOCK, 0, stream>>>(x, wgt, bias, out, n_tokens);
}